// Round 3
// baseline (59.424 us; speedup 1.0000x reference)
//
#include <hip/hip_runtime.h>
#include <hip/hip_bf16.h>

#define B_    64
#define S_    513
#define T_    512
#define H_    1024
#define OUT_  128
#define BK    32
#define BN    32
#define NKT   (H_ / BK)   // 32

typedef __attribute__((ext_vector_type(8))) short short8_t;
typedef __attribute__((ext_vector_type(4))) float f32x4;

__device__ inline ushort f2bf(float f) {
    union { float f; unsigned u; } x; x.f = f;
    unsigned r = x.u + 0x7fffu + ((x.u >> 16) & 1u);   // round-to-nearest-even
    return (ushort)(r >> 16);
}

// staging buffers (70 KB) and epilogue logits tile (67.6 KB) share LDS
union SmemT {
    struct {
        ushort As[2][T_ * BK];    // 512x32 bf16, XOR-swizzled, dbuf
        ushort Bs[2][BN * BK];    // 32(o) x 32(k) bf16, XOR-swizzled, dbuf
    } st;
    float lg[T_ * 33];            // [t][o] padded (+1) logits tile
};

// ---------------------------------------------------------------------------
// ONE kernel: seg-info + GEMM(bf16 MFMA) + bias + segment-mean + transposed
// store. Block = (batch, 32-wide o-tile); full T=512 rows per block so
// segments never cross blocks. 512 threads = 8 waves, wave tile 64x32.
// grid 256 = 1 block/CU; same-batch blocks share an XCD for A L2 reuse.
// ---------------------------------------------------------------------------
__global__ __launch_bounds__(512, 2) void fused_kernel(
    const float* __restrict__ hs, const float* __restrict__ W,
    const float* __restrict__ bias, const int* __restrict__ seg,
    float* __restrict__ out)
{
    __shared__ SmemT sm;
    __shared__ int s_start[T_];
    __shared__ int s_cnt[T_];

    int d = blockIdx.x;
    // XCD swizzle: dispatch d -> XCD d%8 (assumed); keep a batch's 4 o-tiles
    // on one XCD so the 4x A re-read hits its private L2.
    int batch = (d & 7) + ((d >> 5) << 3);
    int o0    = ((d >> 3) & 3) * BN;

    int tid  = threadIdx.x;
    int lane = tid & 63;
    int w    = tid >> 6;          // wave 0..7, owns rows [64w, 64w+64)
    int l15  = lane & 15, ksl = lane >> 4;

    // ---- segment info (contiguous runs): start & count per segment id ----
    s_start[tid] = T_;
    s_cnt[tid]   = 0;
    __syncthreads();
    {
        int sid = seg[batch * T_ + tid];
        atomicMin(&s_start[sid], tid);
        atomicAdd(&s_cnt[sid], 1);
    }
    // (consumed in epilogue; K-loop barriers order this)

    // ---- A staging coords: thread covers 16B (4 floats) of a row, 8 passes
    int arow = tid >> 3;          // 0..63  (+64 per pass)
    int ac8  = tid & 7;           // 4-float chunk within BK
    const float* aptr = hs + ((size_t)(batch * S_ + 1 + arow)) * H_ + ac8 * 4;
    // swizzle component is pass-invariant: (row>>1)&3 unchanged by +64
    int wAbase = arow * BK + ((((ac8 >> 1) ^ ((arow >> 1) & 3))) << 3)
               + ((ac8 & 1) << 2);

    // ---- W staging coords: thread loads 2 floats of W[k][o0+..], writes
    // transposed into Bs[o][k] (scattered u16, tiny)
    int wk = tid >> 4;            // 0..31
    int wo = (tid & 15) * 2;      // 0..30 even
    const float* wptr = W + (size_t)wk * OUT_ + o0 + wo;
    int wBo0 = wo * BK + (((wk >> 3) ^ ((wo >> 1) & 3)) << 3) + (wk & 7);
    // wo+1 has same swizzle (wo even) -> +BK

    // ---- fragment read offsets (b128, swizzle-consistent) ----
    int rAo[4], rBo[2];
#pragma unroll
    for (int fm = 0; fm < 4; ++fm) {
        int row = w * 64 + fm * 16 + l15;
        rAo[fm] = row * BK + ((ksl ^ ((row >> 1) & 3)) << 3);
    }
#pragma unroll
    for (int fn = 0; fn < 2; ++fn) {
        int o = fn * 16 + l15;
        rBo[fn] = o * BK + ((ksl ^ ((o >> 1) & 3)) << 3);
    }

    f32x4 acc[4][2];
#pragma unroll
    for (int fm = 0; fm < 4; ++fm)
#pragma unroll
        for (int fn = 0; fn < 2; ++fn) acc[fm][fn] = (f32x4){0.f, 0.f, 0.f, 0.f};

    float4 ra[8];
    float2 rw;

    auto loadT = [&](int kt) {
        const float* ap = aptr + kt * BK;
#pragma unroll
        for (int p = 0; p < 8; ++p)
            ra[p] = *reinterpret_cast<const float4*>(ap + (size_t)p * 64 * H_);
        rw = *reinterpret_cast<const float2*>(wptr + (size_t)kt * BK * OUT_);
    };
    auto writeT = [&](int nb) {
#pragma unroll
        for (int p = 0; p < 8; ++p) {
            union { ushort u[4]; uint2 v; } pk;
            pk.u[0] = f2bf(ra[p].x); pk.u[1] = f2bf(ra[p].y);
            pk.u[2] = f2bf(ra[p].z); pk.u[3] = f2bf(ra[p].w);
            *reinterpret_cast<uint2*>(&sm.st.As[nb][wAbase + p * 64 * BK]) = pk.v;
        }
        sm.st.Bs[nb][wBo0]      = f2bf(rw.x);
        sm.st.Bs[nb][wBo0 + BK] = f2bf(rw.y);
    };
    auto computeT = [&](int cb) {
        short8_t af[4], bfr[2];
#pragma unroll
        for (int fm = 0; fm < 4; ++fm)
            af[fm] = *reinterpret_cast<const short8_t*>(&sm.st.As[cb][rAo[fm]]);
#pragma unroll
        for (int fn = 0; fn < 2; ++fn)
            bfr[fn] = *reinterpret_cast<const short8_t*>(&sm.st.Bs[cb][rBo[fn]]);
#pragma unroll
        for (int fm = 0; fm < 4; ++fm)
#pragma unroll
            for (int fn = 0; fn < 2; ++fn)
                acc[fm][fn] = __builtin_amdgcn_mfma_f32_16x16x32_bf16(
                    af[fm], bfr[fn], acc[fm][fn], 0, 0, 0);
    };

    loadT(0);
    writeT(0);
    __syncthreads();

    for (int kt = 0; kt < NKT; ++kt) {
        int cb = kt & 1;
        if (kt + 1 < NKT) loadT(kt + 1);
        computeT(cb);
        if (kt + 1 < NKT) writeT(cb ^ 1);
        __syncthreads();
    }

    // ---- epilogue: acc (+bias) -> lg[t][o] in LDS ----
    float bv0 = bias[o0 + l15];
    float bv1 = bias[o0 + 16 + l15];
#pragma unroll
    for (int fm = 0; fm < 4; ++fm) {
#pragma unroll
        for (int fn = 0; fn < 2; ++fn) {
            float bv = fn ? bv1 : bv0;
            int o = fn * 16 + l15;
#pragma unroll
            for (int r = 0; r < 4; ++r) {
                int t = w * 64 + fm * 16 + ksl * 4 + r;
                sm.lg[t * 33 + o] = acc[fm][fn][r] + bv;
            }
        }
    }
    __syncthreads();

    // ---- segment means + transposed store: out[b][o][s], coalesced in s ----
#pragma unroll
    for (int it = 0; it < 32; ++it) {
        int idx = tid + it * 512;     // 0..16383
        int o   = idx >> 9;           // 0..31
        int s   = idx & 511;
        int cnt = s_cnt[s];
        float v = 0.f;
        if (cnt > 0) {
            int st = s_start[s];
            float sum = 0.f;
            for (int i = 0; i < cnt; ++i)
                sum += sm.lg[(st + i) * 33 + o];
            v = sum / (float)cnt;
        }
        out[((size_t)batch * OUT_ + o0 + o) * T_ + s] = v;
    }
}

// ---------------------------------------------------------------------------
extern "C" void kernel_launch(void* const* d_in, const int* in_sizes, int n_in,
                              void* d_out, int out_size, void* d_ws, size_t ws_size,
                              hipStream_t stream) {
    const float* hs   = (const float*)d_in[0];   // (B, S, H)
    const float* W    = (const float*)d_in[1];   // (H, OUT)
    const float* bias = (const float*)d_in[2];   // (OUT,)
    const int*   seg  = (const int*)d_in[3];     // (B, T)
    float* out = (float*)d_out;                  // (B, OUT, T)

    fused_kernel<<<B_ * (OUT_ / BN), 512, 0, stream>>>(hs, W, bias, seg, out);
}